// Round 7
// baseline (47834.662 us; speedup 1.0000x reference)
//
#include <hip/hip_runtime.h>
#include <hip/hip_bf16.h>
#include <cstddef>

#define B     32
#define TENC  200
#define E     512
#define D     1024
#define P     256
#define M     80
#define TDEC  600
#define A     128
#define KC    31
#define LF    32

typedef __attribute__((ext_vector_type(8))) short short8;
typedef __attribute__((ext_vector_type(4))) float float4v;
typedef __attribute__((ext_vector_type(2))) unsigned int uint2v;
typedef unsigned short u16;

// output offsets (floats)
#define SPEC_OFF  0
#define STOP_OFF  ((size_t)B * TDEC * M)
#define ALIGN_OFF (STOP_OFF + (size_t)B * TDEC)

// ---------------- workspace layout (float units) ----------------
constexpr size_t OFF_PM   = 0;                    // fp32 [b][t][a]   819200
constexpr size_t OFF_PREB = 819200;               // bf16 fragment-major [t][8192] 2457600 f
constexpr size_t OFF_KPK  = 3276800;              // bf16 packed keff 8192 -> 4096 f
constexpr size_t OFF_WQB  = 3280896;              // bf16 Wq 131072 -> 65536 f
constexpr size_t OFF_FWB  = 3346432;              // bf16 frame/stop W 81*1536 -> 62208 f
constexpr size_t OFF_ST   = 3408640;
// state region (zeroed each call), float offsets relative to OFF_ST:
constexpr size_t ST_HAB0 = 0;       // bf16 fragment-major 32768 u16 -> 16384 f
constexpr size_t ST_HAB1 = 16384;
constexpr size_t ST_HGB0 = 32768;
constexpr size_t ST_HGB1 = 49152;
constexpr size_t ST_CTXB = 65536;   // bf16 fragment-major 16384 u16 -> 8192 f
constexpr size_t ST_CTXF = 73728;   // fp32 2 x [b][512] -> 32768 f
constexpr size_t ST_HGF  = 106496;  // fp32 [b][1024] -> 32768 f
constexpr size_t ST_BARS = 139264;  // 1344 f barrier counters + release lines
constexpr size_t ST_CLAIM = 140608; // 8 u32 leader claims (32 f reserved)
constexpr size_t ST_TAGS  = 140640; // 8 tags x 32 f stride = 256 f
constexpr size_t ST_FAIL  = 140896; // fail counter (32 f)
constexpr size_t ST_CALLID= 140928; // call id slot (32 f)
constexpr size_t ST_XFLG  = 140960; // 8 per-XCD step flags x 32 f = 256 f
constexpr size_t N_STATE  = 141216;
// persistent (NOT memset) region:
constexpr size_t OFF_CALLCTR = OFF_ST + N_STATE;  // 32 f
constexpr size_t OFF_STAGE   = OFF_CALLCTR + 32;  // 8 xcd * 32768 f (hA 64KB + hG 64KB bf16)

// ---------------- LDS layout (bytes) ----------------
constexpr int LDS_ATTW = 0;          // 56*512*2  = 57344
constexpr int LDS_GENW = 57344;      // 80*512*2  = 81920
constexpr int LDS_SC   = 139264;     // 5184 floats scratch (20736 B)
constexpr int LDS_SP   = 160000;     // 232 f padded wprev
constexpr int LDS_SCM  = 160928;     // 232 f padded wcum
constexpr int LDS_CA   = 161856;     // 128 f
constexpr int LDS_CG   = 162368;     // 128 f
constexpr int LDS_FLG  = 162880;     // 2 ints: use_stage, leader
constexpr int SMEM_BYTES = 162944;   // <= 163840

struct Params {
  const float* enc; const int* lens;
  const float *att_Wih, *att_Whh, *att_b, *gen_Wih, *gen_Whh, *gen_b;
  const float *v_att, *b_att, *frame_b, *stop_b;
  const float *pm;
  const u16 *preB, *kpk, *wqb, *fwb;
  u16 *hAb0, *hAb1, *hGb0, *hGb1, *ctxb;
  float *ctxf, *hGf;
  unsigned* bars;
  unsigned *claimv, *tags, *failv, *callid, *callctr, *xflg;
  u16* stage;
  float* out;
};

__device__ __forceinline__ float sigmoidf(float x) { return 1.0f / (1.0f + __expf(-x)); }
__device__ __forceinline__ float tanhfast(float x) {
  float ax = fabsf(x);
  float e = __expf(2.0f * ax);
  float t = 1.0f - 2.0f / (e + 1.0f);
  return copysignf(t, x);
}
__device__ __forceinline__ u16 f2bf(float x) {
  __hip_bfloat16 h = __float2bfloat16(x);
  return __builtin_bit_cast(u16, h);
}
__device__ __forceinline__ float bf2f(u16 u) {
  unsigned v = ((unsigned)u) << 16;
  return __builtin_bit_cast(float, v);
}

// ---- load/store helpers ----
// MALL-coherent (bypass non-coherent per-XCD L2):
#define LDC(r, p) asm volatile("global_load_dwordx4 %0, %1, off sc0 sc1" : "=v"(r) : "v"(p))
// plain cached load (immutable data):
#define LDP(r, p) asm volatile("global_load_dwordx4 %0, %1, off" : "=v"(r) : "v"(p))
// L1-bypass, L2-served load (XCD-local staged data):
#define LDS0(r, p) asm volatile("global_load_dwordx4 %0, %1, off sc0" : "=v"(r) : "v"(p))
// plain store (allocates in local XCD L2):
#define STP4(p, v) asm volatile("global_store_dwordx4 %0, %1, off" :: "v"(p), "v"(v) : "memory")

__device__ __forceinline__ float4v ldc1(const void* p) {
  float4v r;
  LDC(r, p);
  asm volatile("s_waitcnt vmcnt(0)" : "+v"(r) :: "memory");
  return r;
}
__device__ __forceinline__ void stc_f32(float* p, float v) {
  asm volatile("global_store_dword %0, %1, off sc0 sc1" :: "v"(p), "v"(v) : "memory");
}
__device__ __forceinline__ void stc_u16(u16* p, u16 v) {
  unsigned vv = v;
  asm volatile("global_store_short %0, %1, off sc0 sc1" :: "v"(p), "v"(vv) : "memory");
}
__device__ __forceinline__ void stc_8B(void* p, uint2v v) {
  asm volatile("global_store_dwordx2 %0, %1, off sc0 sc1" :: "v"(p), "v"(v) : "memory");
}
__device__ __forceinline__ void stc_16B(void* p, float4v v) {
  asm volatile("global_store_dwordx4 %0, %1, off sc0 sc1" :: "v"(p), "v"(v) : "memory");
}
__device__ __forceinline__ void st_u32_plain(unsigned* p, unsigned v) {
  asm volatile("global_store_dword %0, %1, off" :: "v"(p), "v"(v) : "memory");
}
__device__ __forceinline__ unsigned ld_u32_sc0(const unsigned* p) {
  unsigned r;
  asm volatile("global_load_dword %0, %1, off sc0" : "=v"(r) : "v"(p));
  asm volatile("s_waitcnt vmcnt(0)" : "+v"(r) :: "memory");
  return r;
}

// xcd id (validated at runtime; any garbage triggers safe fallback)
__device__ __forceinline__ unsigned read_xcd() {
  unsigned x = __builtin_amdgcn_s_getreg((3u << 11) | 20u);  // HW_REG_XCC_ID, 4 bits
  return x & 7u;
}

// ---------------------------------------------------------------------------
// grid barrier WITHOUT agent-scope fences (no L2 invalidate).  Arrival: 16
// group counters + central.  Release: 16 per-group lines.
__device__ __forceinline__ void gbar(unsigned* bars, int ep) {
  __syncthreads();
  if (threadIdx.x == 0) {
    const int grp = blockIdx.x >> 4;          // 16 groups x 16 blocks
    unsigned old = atomicAdd(bars + (grp << 5), 1u);
    if (old + 1u == (unsigned)ep * 16u) {
      unsigned cold = atomicAdd(bars + 768, 1u);
      if (cold + 1u == (unsigned)ep * 16u) {
        #pragma unroll
        for (int g2 = 0; g2 < 16; ++g2)
          __hip_atomic_store(bars + 800 + (g2 << 5), (unsigned)ep,
                             __ATOMIC_RELAXED, __HIP_MEMORY_SCOPE_AGENT);
      }
    }
    while (__hip_atomic_load(bars + 800 + (grp << 5), __ATOMIC_RELAXED,
                             __HIP_MEMORY_SCOPE_AGENT) < (unsigned)ep)
      __builtin_amdgcn_s_sleep(2);
  }
  __syncthreads();
}

// ---------------------------------------------------------------------------
__device__ __forceinline__ void frame_phase(const Params& p, int ft, int fi, int tid, float* X)
{
  const int bb0 = fi * 2;
  const int slot = ft & 1;
  for (int i = tid; i < 768; i += 512) {
    int bbl = i / 384, r = i - bbl * 384;
    const float* src = (r < 256)
        ? (p.hGf + (size_t)(bb0 + bbl) * 1024 + (size_t)r * 4)
        : (p.ctxf + (size_t)slot * (E * B) + (size_t)(bb0 + bbl) * 512 + (size_t)(r - 256) * 4);
    float4v v = ldc1(src);
    float* dst = X + bbl * 1536 + ((r < 256) ? r * 4 : 1024 + (r - 256) * 4);
    *(float4v*)dst = v;
  }
  __syncthreads();
  if (tid < 324) {
    int bbl = tid / 162, r = tid - bbl * 162, j = r >> 1, half = r & 1;
    const u16* w = p.fwb + (size_t)j * 1536 + half * 768;
    const float* x = X + bbl * 1536 + half * 768;
    float acc = half ? 0.f : ((j < M) ? p.frame_b[j] : p.stop_b[0]);
    float acc2 = 0.f;
    #pragma unroll 8
    for (int k8 = 0; k8 < 96; k8 += 2) {
      short8 wv8 = *(const short8*)(w + k8 * 8);
      #pragma unroll
      for (int jj = 0; jj < 8; ++jj) acc += bf2f((u16)wv8[jj]) * x[k8 * 8 + jj];
      short8 wv9 = *(const short8*)(w + (k8 + 1) * 8);
      #pragma unroll
      for (int jj = 0; jj < 8; ++jj) acc2 += bf2f((u16)wv9[jj]) * x[(k8 + 1) * 8 + jj];
    }
    acc += acc2;
    acc += __shfl_down(acc, 1, 64);
    if (half == 0) {
      int b = bb0 + bbl;
      if (j < M) p.out[SPEC_OFF + (size_t)b * TDEC * M + (size_t)ft * M + j] = acc;
      else       p.out[STOP_OFF + (size_t)b * TDEC + ft] = acc;
    }
  }
  __syncthreads();
}

// ---------------------------------------------------------------------------
// Fragment-major layouts (u16 offsets), global k-chunk index kappa:
//   off = kappa*1024 + (m>>4)*512 + lane*8   (consumer wave reads 1KB bursts)

__global__ void __launch_bounds__(512) persist_kernel(Params p) {
  extern __shared__ char smem[];
  __hip_bfloat16* attw = (__hip_bfloat16*)(smem + LDS_ATTW);
  __hip_bfloat16* genw = (__hip_bfloat16*)(smem + LDS_GENW);
  float* sc   = (float*)(smem + LDS_SC);
  float* sp   = (float*)(smem + LDS_SP);
  float* scm  = (float*)(smem + LDS_SCM);
  float* cAl  = (float*)(smem + LDS_CA);
  float* cGl  = (float*)(smem + LDS_CG);
  int*   flg  = (int*)(smem + LDS_FLG);
  float* hq    = sc;
  float* qpart = sc + 1024;
  float* query = sc + 1536;
  float* red   = sc + 1664;
  u16*   Abuf  = (u16*)(smem + LDS_SC + 6784);
  float* epart = sc + 3360;
  float* e_w   = sc + 4960;
  float* hstg  = sc + 4200;

  const int tid  = threadIdx.x;
  const int blk  = blockIdx.x;
  const int lane = tid & 63;
  const int wv   = tid >> 6;
  const int bb = blk >> 3;
  const bool is_att = ((blk & 7) == (bb & 7));
  const int fi = blk >> 3;
  const bool is_frame = (fi < 16) && ((blk & 7) == ((fi + 4) & 7));
  const bool is_idle = !is_att && !is_frame;
  const unsigned g = read_xcd();
  int ep = 0;

  // ============ prolog: pack weight slices into LDS ============
  for (int idx = tid; idx < 56 * 512; idx += 512) {
    int k0 = idx >> 9, e = idx & 511, ln = e >> 3, j = e & 7, r = ln & 15;
    int row = (r & 3) * D + blk * 4 + (r >> 2);
    int kq8 = ((ln >> 4) << 3) + j;
    int w = k0 / 14, s = k0 - w * 14;
    float v;
    if (s < 2) {
      int k = (w * 2 + s) * 32 + kq8;
      v = p.att_Wih[(size_t)row * 768 + k];
    } else if (s < 10) {
      int kk = (w * 8 + (s - 2)) * 32 + kq8;
      v = p.att_Whh[(size_t)row * D + kk];
    } else {
      int k = 256 + (w * 4 + (s - 10)) * 32 + kq8;
      v = p.att_Wih[(size_t)row * 768 + k];
    }
    attw[idx] = __float2bfloat16(v);
  }
  for (int idx = tid; idx < 80 * 512; idx += 512) {
    int k0 = idx >> 9, e = idx & 511, ln = e >> 3, j = e & 7, r = ln & 15;
    int row = (r & 3) * D + blk * 4 + (r >> 2);
    int kq8 = ((ln >> 4) << 3) + j;
    int w = k0 / 20, s = k0 - w * 20;
    float v;
    if (s < 8) {
      int k = (w * 8 + s) * 32 + kq8;
      v = p.gen_Wih[(size_t)row * 1536 + k];
    } else if (s < 16) {
      int kk = (w * 8 + (s - 8)) * 32 + kq8;
      v = p.gen_Whh[(size_t)row * D + kk];
    } else {
      int k = 1024 + (w * 4 + (s - 16)) * 32 + kq8;
      v = p.gen_Wih[(size_t)row * 1536 + k];
    }
    genw[idx] = __float2bfloat16(v);
  }
  if (tid < 128) { cAl[tid] = 0.f; cGl[tid] = 0.f; }
  for (int i = tid; i < 232; i += 512) { sp[i] = 0.f; scm[i] = 0.f; }
  if (tid == 0) { flg[0] = 0; flg[1] = 0; }
  __syncthreads();

  // ============ prolog: staging validation handshake (proven in r3) ============
  if (blk == 0 && tid == 0) {
    unsigned old = atomicAdd(p.callctr, 1u);
    atomicExch(p.callid, old + 1u);
  }
  gbar(p.bars, ++ep);  // ep 1
  unsigned callv = __hip_atomic_load(p.callid, __ATOMIC_RELAXED, __HIP_MEMORY_SCOPE_AGENT);
  const unsigned magicA = (callv * 2654435761u) | 0x80000001u;
  const unsigned magicB = magicA ^ 0x00FF00FFu;
  if (tid == 0 && is_idle) {
    unsigned rank = atomicAdd(p.claimv + g, 1u);
    if (rank == 0u) {
      flg[1] = 1;  // leader
      st_u32_plain(p.tags + (size_t)g * 32, magicA);
      asm volatile("s_waitcnt vmcnt(0)" ::: "memory");
    }
  }
  gbar(p.bars, ++ep);  // ep 2
  if (tid == 0) {
    if (ld_u32_sc0(p.tags + (size_t)g * 32) != magicA) atomicAdd(p.failv, 1u);
  }
  gbar(p.bars, ++ep);  // ep 3
  if (tid == 0 && flg[1]) {
    st_u32_plain(p.tags + (size_t)g * 32, magicB);
    asm volatile("s_waitcnt vmcnt(0)" ::: "memory");
  }
  gbar(p.bars, ++ep);  // ep 4
  if (tid == 0) {
    if (ld_u32_sc0(p.tags + (size_t)g * 32) != magicB) atomicAdd(p.failv, 1u);
  }
  gbar(p.bars, ++ep);  // ep 5
  if (tid == 0) {
    unsigned f = __hip_atomic_load(p.failv, __ATOMIC_RELAXED, __HIP_MEMORY_SCOPE_AGENT);
    flg[0] = (f == 0u) ? 1 : 0;
  }
  __syncthreads();
  const bool use_stage = (flg[0] != 0);
  const bool lead = (flg[1] != 0);

  // per-thread constant geometry
  const int mt  = wv & 1, kqi = wv >> 1;
  const size_t offPreF = (size_t)kqi * 2048 + (size_t)mt * 512 + (size_t)lane * 8;
  const size_t offHF   = (size_t)kqi * 8192 + (size_t)mt * 512 + (size_t)lane * 8;
  const size_t offCF   = (size_t)kqi * 4096 + (size_t)mt * 512 + (size_t)lane * 8;
  const __hip_bfloat16* awp = attw + (size_t)(kqi * 14) * 512 + (size_t)lane * 8;
  const __hip_bfloat16* gwp = genw + (size_t)(kqi * 20) * 512 + (size_t)lane * 8;
  const int kqiB = blk >> 6, rB = (blk >> 3) & 7, lhB = (blk >> 1) & 3, j0B = (blk & 1) * 4;
  u16* const stg = p.stage + (size_t)g * 65536;  // [hA 32768 u16][hG 32768 u16]

#define MFA(i, reg) accA = __builtin_amdgcn_mfma_f32_16x16x32_bf16( \
    __builtin_bit_cast(short8, reg), *(const short8*)(awp + (size_t)(i) * 512), accA, 0, 0, 0)
#define MFG(i, reg) accG = __builtin_amdgcn_mfma_f32_16x16x32_bf16( \
    __builtin_bit_cast(short8, reg), *(const short8*)(gwp + (size_t)(i) * 512), accG, 0, 0, 0)

#define ISSUE18() do { \
    const u16* _pr = p.preB + (size_t)tp1 * (B * P) + offPreF; \
    const u16* _ha = hAcur + offHF; \
    const u16* _hg = hGprev + offHF; \
    LDP(e0, _pr); LDP(e1, _pr + 1024); \
    LDC(e2, _ha); LDC(e3, _ha + 1024); LDC(e4, _ha + 2048); LDC(e5, _ha + 3072); \
    LDC(e6, _ha + 4096); LDC(e7, _ha + 5120); LDC(e8, _ha + 6144); LDC(e9, _ha + 7168); \
    LDC(e10, _hg); LDC(e11, _hg + 1024); LDC(e12, _hg + 2048); LDC(e13, _hg + 3072); \
    LDC(e14, _hg + 4096); LDC(e15, _hg + 5120); LDC(e16, _hg + 6144); LDC(e17, _hg + 7168); \
  } while (0)

#define ISSUE18_STG() do { \
    const u16* _pr = p.preB + (size_t)tp1 * (B * P) + offPreF; \
    const u16* _ha = stg + offHF; \
    const u16* _hg = stg + 32768 + offHF; \
    LDP(e0, _pr); LDP(e1, _pr + 1024); \
    LDS0(e2, _ha); LDS0(e3, _ha + 1024); LDS0(e4, _ha + 2048); LDS0(e5, _ha + 3072); \
    LDS0(e6, _ha + 4096); LDS0(e7, _ha + 5120); LDS0(e8, _ha + 6144); LDS0(e9, _ha + 7168); \
    LDS0(e10, _hg); LDS0(e11, _hg + 1024); LDS0(e12, _hg + 2048); LDS0(e13, _hg + 3072); \
    LDS0(e14, _hg + 4096); LDS0(e15, _hg + 5120); LDS0(e16, _hg + 6144); LDS0(e17, _hg + 7168); \
  } while (0)

#define SPIN_AND_ISSUE() do { \
    if (tid == 0) { \
      while (ld_u32_sc0(p.xflg + (size_t)g * 32) < (unsigned)(t + 1)) \
        __builtin_amdgcn_s_sleep(1); \
    } \
    __syncthreads(); \
    ISSUE18_STG(); \
  } while (0)

  // ============ pre-phase: att gates for t=0 (ctx=0, hA=0 => only preB term) ============
  {
    const u16* _pr = p.preB + offPreF;
    float4v e0, e1;
    LDP(e0, _pr); LDP(e1, _pr + 1024);
    asm volatile("s_waitcnt vmcnt(0)" : "+v"(e0), "+v"(e1) :: "memory");
    float4v accA = {0.f, 0.f, 0.f, 0.f};
    MFA(0, e0); MFA(1, e1);
    float* r = sc + ((((0 * 2 + mt) * 4 + kqi) * 64 + lane) << 2);
    r[0] = accA[0]; r[1] = accA[1]; r[2] = accA[2]; r[3] = accA[3];
    __syncthreads();
    if (tid < 128) {
      int dj_l = (tid >> 5) & 3, mm = tid & 31;
      int dj = blk * 4 + dj_l;
      int mt2 = mm >> 4, m2 = mm & 15;
      float g4[4];
      #pragma unroll
      for (int gate = 0; gate < 4; ++gate) {
        int ln = ((m2 >> 2) << 4) | (dj_l * 4 + gate);
        int rg = m2 & 3;
        float s = 0.f;
        #pragma unroll
        for (int kk = 0; kk < 4; ++kk)
          s += sc[((((0 * 2 + mt2) * 4 + kk) * 64 + ln) << 2) + rg];
        g4[gate] = s + p.att_b[gate * D + dj];
      }
      float c  = cAl[dj_l * 32 + mm];
      float cn = sigmoidf(g4[1]) * c + sigmoidf(g4[0]) * tanhfast(g4[2]);
      float hn = sigmoidf(g4[3]) * tanhfast(cn);
      cAl[dj_l * 32 + mm] = cn;
      size_t offP = (size_t)(kqiB * 8 + rB) * 1024 + (size_t)(mm >> 4) * 512
                  + (size_t)(lhB * 16 + (mm & 15)) * 8 + j0B + dj_l;
      stc_u16(p.hAb0 + offP, f2bf(hn));
    }
  }
  gbar(p.bars, ++ep);  // ep 6

  // ============ main loop ============
  for (int t = 0; t < TDEC; ++t) {
    const u16* hAcur  = (t & 1) ? p.hAb1 : p.hAb0;
    u16*       hAnxt  = (t & 1) ? p.hAb0 : p.hAb1;
    const u16* hGprev = (t & 1) ? p.hGb0 : p.hGb1;
    u16*       hGcur  = (t & 1) ? p.hGb1 : p.hGb0;
    const int  tp1 = (t + 1 < TDEC) ? (t + 1) : (TDEC - 1);
    const bool doatt = (t < TDEC - 1);

    // PG activation fragments (issued during PA, waited in PG)
    float4v e0,e1,e2,e3,e4,e5,e6,e7,e8,e9,e10,e11,e12,e13,e14,e15,e16,e17;

    // ---- PA: attention (32) + frame t-1 (16) + stage-leader (8) ----
    if (is_att) {
      const int b = bb;
      // 1) stage hA bf16 -> hq fp32 (fragment-major gather: 1 x 16B per thread)
      if (tid < 128) {
        const int kqi2 = tid >> 5, r2 = (tid >> 2) & 7, lh2 = tid & 3;
        float4v hv = ldc1(hAcur + (size_t)(kqi2 * 8 + r2) * 1024 + (size_t)(b >> 4) * 512
                          + (size_t)(lh2 * 16 + (b & 15)) * 8);
        short8 hs = __builtin_bit_cast(short8, hv);
        #pragma unroll
        for (int j = 0; j < 8; ++j) hq[tid * 8 + j] = bf2f((u16)hs[j]);
      }
      __syncthreads();
      // 2) query = hA @ Wq.T
      {
        const int a = tid >> 2, qk = tid & 3;
        const u16* wrow = p.wqb + (size_t)a * 1024 + qk * 256;
        const float* hh = hq + qk * 256;
        float a0 = 0.f, a1 = 0.f;
        #pragma unroll 4
        for (int i = 0; i < 32; i += 2) {
          short8 wv8 = *(const short8*)(wrow + i * 8);
          #pragma unroll
          for (int j = 0; j < 8; ++j) a0 += bf2f((u16)wv8[j]) * hh[i * 8 + j];
          short8 wv9 = *(const short8*)(wrow + (i + 1) * 8);
          #pragma unroll
          for (int j = 0; j < 8; ++j) a1 += bf2f((u16)wv9[j]) * hh[(i + 1) * 8 + j];
        }
        qpart[tid] = a0 + a1;
      }
      __syncthreads();
      if (tid < 128)
        query[tid] = qpart[tid * 4] + qpart[tid * 4 + 1] + qpart[tid * 4 + 2]
                   + qpart[tid * 4 + 3] + p.b_att[tid];
      // 3) location conv as MFMA, two passes (wprev, wcum)
      float4v cacc[13];
      #pragma unroll
      for (int i = 0; i < 13; ++i) cacc[i] = (float4v){0.f, 0.f, 0.f, 0.f};
      const int tn = wv, cl = lane & 15, kq8 = (lane >> 4) << 3;
      #pragma unroll
      for (int pass = 0; pass < 2; ++pass) {
        __syncthreads();
        const float* src = pass ? scm : sp;
        for (int i = tid; i < 6656; i += 512) {
          int r = i >> 5, k = i & 31;
          float v = (r < 200 && k < 31) ? src[r + k] : 0.f;
          Abuf[i] = f2bf(v);
        }
        __syncthreads();
        short8 bfrag = *(const short8*)(p.kpk + ((size_t)(pass * 8 + tn) * 64 + lane) * 8);
        #pragma unroll
        for (int tm = 0; tm < 13; ++tm) {
          short8 av = *(const short8*)(Abuf + (size_t)(tm * 16 + cl) * 32 + kq8);
          cacc[tm] = __builtin_amdgcn_mfma_f32_16x16x32_bf16(av, bfrag, cacc[tm], 0, 0, 0);
        }
      }
      // 4) energies
      {
        const int a = tn * 16 + cl;
        const float qv = query[a];
        const float vv = p.v_att[a];
        #pragma unroll
        for (int tm = 0; tm < 13; ++tm) {
          #pragma unroll
          for (int i = 0; i < 4; ++i) {
            int tt = tm * 16 + ((lane >> 4) << 2) + i;
            float val = 0.f;
            if (tt < 200)
              val = tanhfast(qv + p.pm[((size_t)b * TENC + tt) * A + a] + cacc[tm][i]) * vv;
            val += __shfl_down(val, 8, 16);
            val += __shfl_down(val, 4, 16);
            val += __shfl_down(val, 2, 16);
            val += __shfl_down(val, 1, 16);
            if (cl == 0 && tt < 200) epart[tt * 8 + tn] = val;
          }
        }
      }
      __syncthreads();
      // 5) softmax over 200
      const int len = p.lens[b];
      if (tid < 200) {
        float e = 0.f;
        #pragma unroll
        for (int i = 0; i < 8; ++i) e += epart[tid * 8 + i];
        e_w[tid] = (tid < len) ? e : -1.0e9f;
      }
      __syncthreads();
      float lm = (tid < 200) ? e_w[tid] : -3.0e38f;
      for (int o = 32; o > 0; o >>= 1) lm = fmaxf(lm, __shfl_down(lm, o, 64));
      if (lane == 0) red[wv] = lm;
      __syncthreads();
      float gm = red[0];
      #pragma unroll
      for (int i = 1; i < 8; ++i) gm = fmaxf(gm, red[i]);
      float ls = 0.f;
      float myp = 0.f;
      if (tid < 200) { myp = __expf(e_w[tid] - gm); ls = myp; }
      __syncthreads();
      if (tid < 200) e_w[tid] = myp;
      for (int o = 32; o > 0; o >>= 1) ls += __shfl_down(ls, o, 64);
      if (lane == 0) red[wv] = ls;
      __syncthreads();
      float inv = 0.f;
      #pragma unroll
      for (int i = 0; i < 8; ++i) inv += red[i];
      inv = 1.0f / inv;
      __syncthreads();
      if (tid < 200) {
        float wval = e_w[tid] * inv;
        e_w[tid] = wval;
        sp[15 + tid] = wval;
        scm[15 + tid] += wval;
        p.out[ALIGN_OFF + ((size_t)b * TDEC + t) * TENC + tid] = wval;
      }
      __syncthreads();
      // 6) context = w @ enc[b]
      float ctxv;
      {
        const float* ebase = p.enc + (size_t)b * TENC * E + tid;
        float a0 = 0.f, a1 = 0.f, a2 = 0.f, a3 = 0.f;
        #pragma unroll 5
        for (int tt = 0; tt < 200; tt += 4) {
          a0 += e_w[tt]     * ebase[(size_t)tt * E];
          a1 += e_w[tt + 1] * ebase[(size_t)(tt + 1) * E];
          a2 += e_w[tt + 2] * ebase[(size_t)(tt + 2) * E];
          a3 += e_w[tt + 3] * ebase[(size_t)(tt + 3) * E];
        }
        ctxv = (a0 + a1) + (a2 + a3);
      }
      // packed ctx stores via LDS bounce (hq region is dead now)
      sc[tid] = ctxv;
      ((u16*)(sc + 512))[tid] = f2bf(ctxv);
      __syncthreads();
      if (tid < 128) {
        float4v v = *(float4v*)(sc + tid * 4);
        stc_16B(p.ctxf + (size_t)(t & 1) * (E * B) + (size_t)b * 512 + (size_t)tid * 4, v);
      }
      if (tid < 64) {
        float4v v = *(float4v*)((u16*)(sc + 512) + tid * 8);
        const int kqi3 = tid >> 4, r3 = (tid >> 2) & 3, lh3 = tid & 3;
        stc_16B(p.ctxb + (size_t)(kqi3 * 4 + r3) * 1024 + (size_t)(b >> 4) * 512
                + (size_t)(lh3 * 16 + (b & 15)) * 8, v);
      }
      // issue PG loads (staged if validated; flag is long set by now)
      if (use_stage) { SPIN_AND_ISSUE(); } else { ISSUE18(); }
    } else if (is_frame) {
      if (t > 0) frame_phase(p, t - 1, fi, tid, sc);
      if (use_stage) { SPIN_AND_ISSUE(); } else { ISSUE18(); }
    } else if (use_stage && lead) {
      // leader: copy hA(t) + hG(t-1) MALL -> XCD-local L2 stage, release flag.
      const u16* sa = hAcur + (size_t)tid * 64;
      const u16* sg = hGprev + (size_t)tid * 64;
      float4v a0,a1,a2,a3,a4,a5,a6,a7,b0,b1,b2,b3,b4,b5,b6,b7;
      LDC(a0, sa); LDC(a1, sa + 8); LDC(a2, sa + 16); LDC(a3, sa + 24);
      LDC(a4, sa + 32); LDC(a5, sa + 40); LDC(a6, sa + 48); LDC(a7, sa + 56);
      LDC(b0, sg); LDC(b1, sg + 8); LDC(b2, sg + 16); LDC(b3, sg + 24);
      LDC(b4, sg + 32); LDC(b5, sg + 40); LDC(b6, sg + 48); LDC(b7, sg + 56);
      asm volatile("s_waitcnt vmcnt(0)"
        : "+v"(a0),"+v"(a1),"+v"(a2),"+v"(a3),"+v"(a4),"+v"(a5),"+v"(a6),"+v"(a7),
          "+v"(b0),"+v"(b1),"+v"(b2),"+v"(b3),"+v"(b4),"+v"(b5),"+v"(b6),"+v"(b7)
        :: "memory");
      u16* da = stg + (size_t)tid * 64;
      u16* dg = stg + 32768 + (size_t)tid * 64;
      STP4(da, a0); STP4(da + 8, a1); STP4(da + 16, a2); STP4(da + 24, a3);
      STP4(da + 32, a4); STP4(da + 40, a5); STP4(da + 48, a6); STP4(da + 56, a7);
      STP4(dg, b0); STP4(dg + 8, b1); STP4(dg + 16, b2); STP4(dg + 24, b3);
      STP4(dg + 32, b4); STP4(dg + 40, b5); STP4(dg + 48, b6); STP4(dg + 56, b7);
      asm volatile("s_waitcnt vmcnt(0)" ::: "memory");
      __syncthreads();   // all threads' stage stores complete
      if (tid == 0) st_u32_plain(p.xflg + (size_t)g * 32, (unsigned)(t + 1));
      ISSUE18_STG();
    } else if (use_stage) {
      SPIN_AND_ISSUE();
    } else {
      ISSUE18();
    }
    gbar(p.bars, ++ep);

    // ---- PG: gen gates t + att gates t+1 (all 256 blocks) ----
    {
      const u16* _ct = p.ctxb + offCF;
      float4v c0, c1, c2, c3;
      LDC(c0, _ct); LDC(c1, _ct + 1024); LDC(c2, _ct + 2048); LDC(c3, _ct + 3072);
      // fragments first (ctx still in flight)
      asm volatile("s_waitcnt vmcnt(4)"
        : "+v"(e0),"+v"(e1),"+v"(e2),"+v"(e3),"+v"(e4),"+v"(e5),"+v"(e6),"+v"(e7),
          "+v"(e8),"+v"(e9),"+v"(e10),"+v"(e11),"+v"(e12),"+v"(e13),"+v"(e14),"+v"(e15),
          "+v"(e16),"+v"(e17)
        :: "memory");
      float4v accA = {0.f, 0.f, 0.f, 0.f};
      float4v accG = {0.f, 0.f, 0.f, 0.f};
      MFA(0, e0);  MFA(1, e1);
      MFA(2, e2);  MFG(0, e2);
      MFA(3, e3);  MFG(1, e3);
      MFA(4, e4);  MFG(2, e4);
      MFA(5, e5);  MFG(3, e5);
      MFA(6, e6);  MFG(4, e6);
      MFA(7, e7);  MFG(5, e7);
      MFA(8, e8);  MFG(6, e8);
      MFA(9, e9);  MFG(7, e9);
      MFG(8, e10); MFG(9, e11); MFG(10, e12); MFG(11, e13);
      MFG(12, e14); MFG(13, e15); MFG(14, e16); MFG(15, e17);
      __builtin_amdgcn_sched_barrier(0);
      asm volatile("s_waitcnt vmcnt(0)"
        : "+v"(c0),"+v"(c1),"+v"(c2),"+v"(c3) :: "memory");
      MFA(10, c0); MFG(16, c0);
      MFA(11, c1); MFG(17, c1);
      MFA(12, c2); MFG(18, c2);
      MFA(13, c3); MFG(19, c3);
      float* rA = sc + ((((0 * 2 + mt) * 4 + kqi) * 64 + lane) << 2);
      rA[0] = accA[0]; rA[1] = accA[1]; rA[2] = accA[2]; rA[3] = accA[3];
      float* rG = sc + ((((1 * 2 + mt) * 4 + kqi) * 64 + lane) << 2);
      rG[0] = accG[0]; rG[1] = accG[1]; rG[2] = accG[2]; rG[3] = accG[3];
      __syncthreads();
      if (tid < 256) {
        const int gg = tid >> 7, dj_l = (tid >> 5) & 3, mm = tid & 31;
        if (gg == 1 || doatt) {
          const int dj = blk * 4 + dj_l;
          const int mt2 = mm >> 4, m2 = mm & 15;
          const float* bias = (gg == 0) ? p.att_b : p.gen_b;
          float g4[4];
          #pragma unroll
          for (int gate = 0; gate < 4; ++gate) {
            int ln = ((m2 >> 2) << 4) | (dj_l * 4 + gate);
            int rg = m2 & 3;
            float s = 0.f;
            #pragma unroll
            for (int kk = 0; kk < 4; ++kk)
              s += sc[((((gg * 2 + mt2) * 4 + kk) * 64 + ln) << 2) + rg];
            g4[gate] = s + bias[gate * D + dj];
          }
          float* cl2 = (gg == 0) ? cAl : cGl;
          float c  = cl2[dj_l * 32 + mm];
          float cn = sigmoidf(g4[1]) * c + sigmoidf(g4[0]) * tanhfast(g4[2]);
          float hn = sigmoidf(g4[3]) * tanhfast(cn);
          cl2[dj_l * 32 + mm] = cn;
          hstg[tid] = hn;
        }
      }
      __syncthreads();
      // packed fragment-major stores: 64 threads, 8B/16B transactions
      if (tid < 64) {
        const int gg = tid >> 5, mm = tid & 31;
        const size_t offP = (size_t)(kqiB * 8 + rB) * 1024 + (size_t)(mm >> 4) * 512
                          + (size_t)(lhB * 16 + (mm & 15)) * 8 + j0B;
        if (gg == 0) {
          if (doatt) {
            unsigned w0 = (unsigned)f2bf(hstg[mm])      | ((unsigned)f2bf(hstg[32 + mm]) << 16);
            unsigned w1 = (unsigned)f2bf(hstg[64 + mm]) | ((unsigned)f2bf(hstg[96 + mm]) << 16);
            uint2v pk = {w0, w1};
            stc_8B(hAnxt + offP, pk);
          }
        } else {
          float f0 = hstg[128 + mm], f1 = hstg[160 + mm];
          float f2 = hstg[192 + mm], f3 = hstg[224 + mm];
          unsigned w0 = (unsigned)f2bf(f0) | ((unsigned)f2bf(f1) << 16);
          unsigned w1 = (unsigned)f2bf(f2) | ((unsigned)f2bf(f3) << 16);
          uint2v pk = {w0, w1};
          stc_8B(hGcur + offP, pk);
          float4v pf = {f0, f1, f2, f3};
          stc_16B(p.hGf + (size_t)mm * 1024 + blk * 4, pf);
        }
      }
    }
    gbar(p.bars, ++ep);
  }

  // ---- final frame (t = 599) ----
  if (is_frame) frame_phase(p, TDEC - 1, fi, tid, sc);
}

// ---------------------------------------------------------------------------
// Prenet -> preB fragment-major per t
__global__ __launch_bounds__(256) void prenet_kernel(
    const float* __restrict__ target, const float* __restrict__ W1, const float* __restrict__ b1,
    const float* __restrict__ W2, const float* __restrict__ b2, u16* __restrict__ preB)
{
  const int t = blockIdx.x;
  const int tid = threadIdx.x;
  __shared__ float tg[B][M];
  __shared__ float x1[B][P];
  for (int i = tid; i < B * M; i += 256) {
    int b = i / M, m = i - b * M;
    tg[b][m] = (t == 0) ? 0.0f : target[(size_t)b * M * TDEC + (size_t)m * TDEC + (t - 1)];
  }
  __syncthreads();
  for (int i = tid; i < B * P; i += 256) {
    int b = i >> 8, j = i & 255;
    const float* w = W1 + (size_t)j * M;
    float acc = b1[j];
    for (int m = 0; m < M; ++m) acc += w[m] * tg[b][m];
    x1[b][j] = fmaxf(acc, 0.0f);
  }
  __syncthreads();
  for (int i = tid; i < B * P; i += 256) {
    int b = i >> 8, j = i & 255;
    const float* w = W2 + (size_t)j * P;
    float acc = b2[j];
    for (int m = 0; m < P; m += 4)
      acc += w[m]*x1[b][m] + w[m+1]*x1[b][m+1] + w[m+2]*x1[b][m+2] + w[m+3]*x1[b][m+3];
    int kqi = j >> 6, r = (j >> 5) & 1, lh = (j >> 3) & 3, jj = j & 7;
    size_t off = (size_t)(kqi * 2 + r) * 1024 + (size_t)(b >> 4) * 512
               + (size_t)(lh * 16 + (b & 15)) * 8 + jj;
    preB[(size_t)t * (B * P) + off] = f2bf(fmaxf(acc, 0.0f));
  }
}

// ---------------------------------------------------------------------------
__global__ __launch_bounds__(256) void procmem_kernel(
    const float* __restrict__ enc, const float* __restrict__ Wm, float* __restrict__ pm)
{
  const int blk = blockIdx.x;
  const int b = blk >> 3;
  const int t0 = (blk & 7) * 25;
  for (int i = threadIdx.x; i < 25 * A; i += 256) {
    int tl = i >> 7, a = i & 127;
    int t = t0 + tl;
    const float* x = enc + ((size_t)b * TENC + t) * E;
    const float* w = Wm + (size_t)a * E;
    float acc = 0.0f;
    for (int k = 0; k < E; k += 4)
      acc += w[k]*x[k] + w[k+1]*x[k+1] + w[k+2]*x[k+2] + w[k+3]*x[k+3];
    pm[((size_t)b * TENC + t) * A + a] = acc;
  }
}

// ---------------------------------------------------------------------------
__global__ __launch_bounds__(256) void kpk_kernel(
    const float* __restrict__ lker, const float* __restrict__ Wloc, u16* __restrict__ kpk)
{
  int idx = blockIdx.x * 256 + threadIdx.x;
  if (idx >= 8192) return;
  int j = idx & 7, ln = (idx >> 3) & 63, tn = (idx >> 9) & 7, pass = idx >> 12;
  int a = tn * 16 + (ln & 15);
  int k = ((ln >> 4) << 3) + j;
  float v = 0.f;
  if (k < KC) {
    for (int f = 0; f < LF; ++f)
      v += Wloc[a * LF + f] * lker[f * (2 * KC) + pass * KC + k];
  }
  kpk[idx] = f2bf(v);
}

// ---------------------------------------------------------------------------
__global__ __launch_bounds__(256) void wqpack_kernel(
    const float* __restrict__ Wq, u16* __restrict__ wqb)
{
  int idx = blockIdx.x * 256 + threadIdx.x;
  if (idx < A * D) wqb[idx] = f2bf(Wq[idx]);
}

// ---------------------------------------------------------------------------
// fwb[j][k]: j=0..79 frame rows, j=80 stop row; bf16
__global__ __launch_bounds__(256) void fwpack_kernel(
    const float* __restrict__ frame_W, const float* __restrict__ stop_W, u16* __restrict__ fwb)
{
  int idx = blockIdx.x * 256 + threadIdx.x;
  if (idx >= 81 * 1536) return;
  int j = idx / 1536, k = idx - j * 1536;
  float v = (j < M) ? frame_W[(size_t)j * 1536 + k] : stop_W[k];
  fwb[idx] = f2bf(v);
}

// ---------------------------------------------------------------------------
extern "C" void kernel_launch(void* const* d_in, const int* in_sizes, int n_in,
                              void* d_out, int out_size, void* d_ws, size_t ws_size,
                              hipStream_t stream)
{
  const float* enc      = (const float*)d_in[0];
  const int*   lens     = (const int*)  d_in[1];
  const float* target   = (const float*)d_in[2];
  const float* pW1      = (const float*)d_in[4];
  const float* pb1      = (const float*)d_in[5];
  const float* pW2      = (const float*)d_in[6];
  const float* pb2      = (const float*)d_in[7];
  const float* att_Wih  = (const float*)d_in[8];
  const float* att_Whh  = (const float*)d_in[9];
  const float* att_b    = (const float*)d_in[10];
  const float* gen_Wih  = (const float*)d_in[11];
  const float* gen_Whh  = (const float*)d_in[12];
  const float* gen_b    = (const float*)d_in[13];
  const float* Wq       = (const float*)d_in[14];
  const float* Wm       = (const float*)d_in[15];
  const float* lker     = (const float*)d_in[16];
  const float* Wloc     = (const float*)d_in[17];
  const float* v_att    = (const float*)d_in[18];
  const float* b_att    = (const float*)d_in[19];
  const float* frame_W  = (const float*)d_in[20];
  const float* frame_b  = (const float*)d_in[21];
  const float* stop_W   = (const float*)d_in[22];
  const float* stop_b   = (const float*)d_in[23];

  float* ws = (float*)d_ws;
  float* st = ws + OFF_ST;

  Params p;
  p.enc = enc; p.lens = lens;
  p.att_Wih = att_Wih; p.att_Whh = att_Whh; p.att_b = att_b;
  p.gen_Wih = gen_Wih; p.gen_Whh = gen_Whh; p.gen_b = gen_b;
  p.v_att = v_att; p.b_att = b_att;
  p.frame_b = frame_b; p.stop_b = stop_b;
  p.pm   = ws + OFF_PM;
  p.preB = (const u16*)(ws + OFF_PREB);
  p.kpk  = (const u16*)(ws + OFF_KPK);
  p.wqb  = (const u16*)(ws + OFF_WQB);
  p.fwb  = (const u16*)(ws + OFF_FWB);
  p.hAb0 = (u16*)(st + ST_HAB0);
  p.hAb1 = (u16*)(st + ST_HAB1);
  p.hGb0 = (u16*)(st + ST_HGB0);
  p.hGb1 = (u16*)(st + ST_HGB1);
  p.ctxb = (u16*)(st + ST_CTXB);
  p.ctxf = st + ST_CTXF;
  p.hGf  = st + ST_HGF;
  p.bars = (unsigned*)(st + ST_BARS);
  p.claimv = (unsigned*)(st + ST_CLAIM);
  p.tags   = (unsigned*)(st + ST_TAGS);
  p.failv  = (unsigned*)(st + ST_FAIL);
  p.callid = (unsigned*)(st + ST_CALLID);
  p.xflg   = (unsigned*)(st + ST_XFLG);
  p.callctr= (unsigned*)(ws + OFF_CALLCTR);
  p.stage  = (u16*)(ws + OFF_STAGE);
  p.out  = (float*)d_out;

  hipMemsetAsync((void*)st, 0, N_STATE * sizeof(float), stream);

  kpk_kernel    <<<32, 256, 0, stream>>>(lker, Wloc, (u16*)(ws + OFF_KPK));
  wqpack_kernel <<<512, 256, 0, stream>>>(Wq, (u16*)(ws + OFF_WQB));
  fwpack_kernel <<<486, 256, 0, stream>>>(frame_W, stop_W, (u16*)(ws + OFF_FWB));
  prenet_kernel <<<TDEC, 256, 0, stream>>>(target, pW1, pb1, pW2, pb2, (u16*)(ws + OFF_PREB));
  procmem_kernel<<<256, 256, 0, stream>>>(enc, Wm, ws + OFF_PM);

  hipFuncSetAttribute((const void*)persist_kernel,
                      hipFuncAttributeMaxDynamicSharedMemorySize, SMEM_BYTES);
  persist_kernel<<<256, 512, SMEM_BYTES, stream>>>(p);
}

// Round 8
// 19112.263 us; speedup vs baseline: 2.5028x; 2.5028x over previous
//
#include <hip/hip_runtime.h>
#include <hip/hip_bf16.h>
#include <cstddef>

#define B     32
#define TENC  200
#define E     512
#define D     1024
#define P     256
#define M     80
#define TDEC  600
#define A     128
#define KC    31
#define LF    32

typedef __attribute__((ext_vector_type(8))) short short8;
typedef __attribute__((ext_vector_type(4))) float float4v;
typedef __attribute__((ext_vector_type(2))) unsigned int uint2v;
typedef unsigned short u16;

// output offsets (floats)
#define SPEC_OFF  0
#define STOP_OFF  ((size_t)B * TDEC * M)
#define ALIGN_OFF (STOP_OFF + (size_t)B * TDEC)

// ---------------- workspace layout (float units) ----------------
constexpr size_t OFF_PM   = 0;                    // fp32 [b][t][a]   819200
constexpr size_t OFF_PREB = 819200;               // bf16 fragment-major [t][8192] 2457600 f
constexpr size_t OFF_KPK  = 3276800;              // bf16 packed keff 8192 -> 4096 f
constexpr size_t OFF_WQB  = 3280896;              // bf16 Wq 131072 -> 65536 f
constexpr size_t OFF_FWB  = 3346432;              // bf16 frame/stop W 81*1536 -> 62208 f
constexpr size_t OFF_ST   = 3408640;
// state region (zeroed each call), float offsets relative to OFF_ST:
constexpr size_t ST_HAB0 = 0;       // bf16 fragment-major 32768 u16 -> 16384 f
constexpr size_t ST_HAB1 = 16384;
constexpr size_t ST_HGB0 = 32768;
constexpr size_t ST_HGB1 = 49152;
constexpr size_t ST_CTXB = 65536;   // bf16 fragment-major 16384 u16 -> 8192 f
constexpr size_t ST_CTXF = 73728;   // fp32 2 x [b][512] -> 32768 f
constexpr size_t ST_HGF  = 106496;  // fp32 [b][1024] -> 32768 f
constexpr size_t ST_BARS = 139264;  // 1344 f barrier counters + release lines
constexpr size_t ST_EPS  = 140608;  // fp32 32 x 256 energy exchange = 8192 f
constexpr size_t ST_GC   = 148800;  // 32 group counters x 32 f = 1024 f
constexpr size_t N_STATE = 149824;

// ---------------- LDS layout (bytes) ----------------
constexpr int LDS_ATTW = 0;          // 56*512*2  = 57344
constexpr int LDS_GENW = 57344;      // 80*512*2  = 81920
constexpr int LDS_SC   = 139264;     // 5184 floats scratch (20736 B)
constexpr int LDS_SP   = 160000;     // 232 f padded wprev
constexpr int LDS_SCM  = 160928;     // 232 f padded wcum
constexpr int LDS_CA   = 161856;     // 128 f
constexpr int LDS_CG   = 162368;     // 128 f
constexpr int SMEM_BYTES = 162880;   // <= 163840

struct Params {
  const float* enc; const int* lens;
  const float *att_Wih, *att_Whh, *att_b, *gen_Wih, *gen_Whh, *gen_b;
  const float *v_att, *b_att, *frame_b, *stop_b;
  const float *pm;
  const u16 *preB, *kpk, *wqb, *fwb;
  u16 *hAb0, *hAb1, *hGb0, *hGb1, *ctxb;
  float *ctxf, *hGf;
  unsigned* bars;
  float* eps;
  unsigned* gc;
  float* out;
};

__device__ __forceinline__ float sigmoidf(float x) { return 1.0f / (1.0f + __expf(-x)); }
__device__ __forceinline__ float tanhfast(float x) {
  float ax = fabsf(x);
  float e = __expf(2.0f * ax);
  float t = 1.0f - 2.0f / (e + 1.0f);
  return copysignf(t, x);
}
__device__ __forceinline__ u16 f2bf(float x) {
  __hip_bfloat16 h = __float2bfloat16(x);
  return __builtin_bit_cast(u16, h);
}
__device__ __forceinline__ float bf2f(u16 u) {
  unsigned v = ((unsigned)u) << 16;
  return __builtin_bit_cast(float, v);
}

// ---- MALL-coherent access helpers (bypass non-coherent per-XCD L2) ----
#define LDC(r, p) asm volatile("global_load_dwordx4 %0, %1, off sc0 sc1" : "=v"(r) : "v"(p))
// plain cached load (immutable data during the persistent kernel):
#define LDP(r, p) asm volatile("global_load_dwordx4 %0, %1, off" : "=v"(r) : "v"(p))

__device__ __forceinline__ float4v ldc1(const void* p) {
  float4v r;
  LDC(r, p);
  asm volatile("s_waitcnt vmcnt(0)" : "+v"(r) :: "memory");
  return r;
}
__device__ __forceinline__ float ldc_f32(const float* pf) {
  float r;
  asm volatile("global_load_dword %0, %1, off sc0 sc1" : "=v"(r) : "v"(pf));
  asm volatile("s_waitcnt vmcnt(0)" : "+v"(r) :: "memory");
  return r;
}
__device__ __forceinline__ void stc_f32(float* p, float v) {
  asm volatile("global_store_dword %0, %1, off sc0 sc1" :: "v"(p), "v"(v) : "memory");
}
__device__ __forceinline__ void stc_u16(u16* p, u16 v) {
  unsigned vv = v;
  asm volatile("global_store_short %0, %1, off sc0 sc1" :: "v"(p), "v"(vv) : "memory");
}
__device__ __forceinline__ void stc_8B(void* p, uint2v v) {
  asm volatile("global_store_dwordx2 %0, %1, off sc0 sc1" :: "v"(p), "v"(v) : "memory");
}
__device__ __forceinline__ void stc_16B(void* p, float4v v) {
  asm volatile("global_store_dwordx4 %0, %1, off sc0 sc1" :: "v"(p), "v"(v) : "memory");
}

// ---------------------------------------------------------------------------
// grid barrier WITHOUT agent-scope fences.  Arrival: 16 group counters +
// central.  Release: 16 per-group lines (16 pollers/line).
__device__ __forceinline__ void gbar(unsigned* bars, int ep) {
  __syncthreads();
  if (threadIdx.x == 0) {
    const int grp = blockIdx.x >> 4;          // 16 groups x 16 blocks
    unsigned old = atomicAdd(bars + (grp << 5), 1u);
    if (old + 1u == (unsigned)ep * 16u) {
      unsigned cold = atomicAdd(bars + 768, 1u);
      if (cold + 1u == (unsigned)ep * 16u) {
        #pragma unroll
        for (int g2 = 0; g2 < 16; ++g2)
          __hip_atomic_store(bars + 800 + (g2 << 5), (unsigned)ep,
                             __ATOMIC_RELAXED, __HIP_MEMORY_SCOPE_AGENT);
      }
    }
    while (__hip_atomic_load(bars + 800 + (grp << 5), __ATOMIC_RELAXED,
                             __HIP_MEMORY_SCOPE_AGENT) < (unsigned)ep)
      __builtin_amdgcn_s_sleep(2);
  }
  __syncthreads();
}

// ---------------------------------------------------------------------------
// Group-distributed frame/stop projection for step ft, batch b, slice k.
// Block k computes rows [k*10, k*10+10) (+ stop row 80 for k==0).
__device__ __forceinline__ void frame_group(const Params& p, int ft, int b, int k,
                                            int wv, int lane, int tid, float* X)
{
  const int slot = ft & 1;
  if (tid < 384) {
    const float* src = (tid < 256)
        ? (p.hGf + (size_t)b * 1024 + (size_t)tid * 4)
        : (p.ctxf + (size_t)slot * (E * B) + (size_t)b * 512 + (size_t)(tid - 256) * 4);
    float4v v = ldc1(src);
    *(float4v*)(X + tid * 4) = v;
  }
  __syncthreads();
  const int nrows = (k == 0) ? 11 : 10;
  for (int jj = wv; jj < nrows; jj += 8) {
    int row = (jj < 10) ? (k * 10 + jj) : 80;
    const u16* w = p.fwb + (size_t)row * 1536 + lane;
    float acc = 0.f, acc2 = 0.f;
    #pragma unroll
    for (int i = 0; i < 24; i += 2) {
      acc  += bf2f(w[(size_t)i * 64])       * X[lane + i * 64];
      acc2 += bf2f(w[(size_t)(i + 1) * 64]) * X[lane + (i + 1) * 64];
    }
    acc += acc2;
    for (int o = 32; o > 0; o >>= 1) acc += __shfl_down(acc, o, 64);
    if (lane == 0) {
      if (row < M) p.out[SPEC_OFF + (size_t)b * TDEC * M + (size_t)ft * M + row] = acc + p.frame_b[row];
      else         p.out[STOP_OFF + (size_t)b * TDEC + ft] = acc + p.stop_b[0];
    }
  }
  __syncthreads();
}

// ---------------------------------------------------------------------------
// Fragment-major layouts (u16 offsets), global k-chunk index kappa:
//   off = kappa*1024 + (m>>4)*512 + lane*8   (consumer wave reads 1KB bursts)

__global__ void __launch_bounds__(512, 2) persist_kernel(Params p) {
  extern __shared__ char smem[];
  __hip_bfloat16* attw = (__hip_bfloat16*)(smem + LDS_ATTW);
  __hip_bfloat16* genw = (__hip_bfloat16*)(smem + LDS_GENW);
  float* sc   = (float*)(smem + LDS_SC);
  float* sp   = (float*)(smem + LDS_SP);
  float* scm  = (float*)(smem + LDS_SCM);
  float* cAl  = (float*)(smem + LDS_CA);
  float* cGl  = (float*)(smem + LDS_CG);
  // PA-phase scratch sublayout (time-multiplexed):
  float* hq    = sc;                       // [0..1024)   gather
  float* qpart = sc + 1024;                // [1024..1536)
  float* query = sc + 1536;                // [1536..1664)
  float* red   = sc + 1664;                // [1664..1672)
  u16*   Abuf  = (u16*)(smem + LDS_SC + 6784);   // floats [1696..5024)
  float* epart = sc + 3360;                // [3360..4960) (after Abuf use)
  float* e_w   = sc + 4960;                // [4960..5160)
  float* Xf    = sc;                       // frame proto [0..1536) (after query)
  float* cpart = sc + 2048;                // ctx partials [2048..2560)
  float* csum  = sc + 2560;                // ctx sums [2560..2624)
  float* hstg  = sc + 4200;                // PG epilogue hn stage (PG-phase only)

  const int tid  = threadIdx.x;
  const int blk  = blockIdx.x;
  const int lane = tid & 63;
  const int wv   = tid >> 6;
  const int b    = blk >> 3;   // group = batch
  const int k    = blk & 7;    // slice within group
  int ep = 0;

  // ============ prolog: pack weight slices into LDS (unchanged scheme) ============
  for (int idx = tid; idx < 56 * 512; idx += 512) {
    int k0 = idx >> 9, e = idx & 511, ln = e >> 3, j = e & 7, r = ln & 15;
    int row = (r & 3) * D + blk * 4 + (r >> 2);
    int kq8 = ((ln >> 4) << 3) + j;
    int w = k0 / 14, s = k0 - w * 14;
    float v;
    if (s < 2) {
      int kk = (w * 2 + s) * 32 + kq8;
      v = p.att_Wih[(size_t)row * 768 + kk];
    } else if (s < 10) {
      int kk = (w * 8 + (s - 2)) * 32 + kq8;
      v = p.att_Whh[(size_t)row * D + kk];
    } else {
      int kk = 256 + (w * 4 + (s - 10)) * 32 + kq8;
      v = p.att_Wih[(size_t)row * 768 + kk];
    }
    attw[idx] = __float2bfloat16(v);
  }
  for (int idx = tid; idx < 80 * 512; idx += 512) {
    int k0 = idx >> 9, e = idx & 511, ln = e >> 3, j = e & 7, r = ln & 15;
    int row = (r & 3) * D + blk * 4 + (r >> 2);
    int kq8 = ((ln >> 4) << 3) + j;
    int w = k0 / 20, s = k0 - w * 20;
    float v;
    if (s < 8) {
      int kk = (w * 8 + s) * 32 + kq8;
      v = p.gen_Wih[(size_t)row * 1536 + kk];
    } else if (s < 16) {
      int kk = (w * 8 + (s - 8)) * 32 + kq8;
      v = p.gen_Whh[(size_t)row * D + kk];
    } else {
      int kk = 1024 + (w * 4 + (s - 16)) * 32 + kq8;
      v = p.gen_Wih[(size_t)row * 1536 + kk];
    }
    genw[idx] = __float2bfloat16(v);
  }
  if (tid < 128) { cAl[tid] = 0.f; cGl[tid] = 0.f; }
  for (int i = tid; i < 232; i += 512) { sp[i] = 0.f; scm[i] = 0.f; }
  __syncthreads();

  // per-thread constant geometry
  const int mt  = wv & 1, kqi = wv >> 1;
  const size_t offPreF = (size_t)kqi * 2048 + (size_t)mt * 512 + (size_t)lane * 8;
  const size_t offHF   = (size_t)kqi * 8192 + (size_t)mt * 512 + (size_t)lane * 8;
  const size_t offCF   = (size_t)kqi * 4096 + (size_t)mt * 512 + (size_t)lane * 8;
  const __hip_bfloat16* awp = attw + (size_t)(kqi * 14) * 512 + (size_t)lane * 8;
  const __hip_bfloat16* gwp = genw + (size_t)(kqi * 20) * 512 + (size_t)lane * 8;
  const int kqiB = blk >> 6, rB = (blk >> 3) & 7, lhB = (blk >> 1) & 3, j0B = (blk & 1) * 4;

#define MFA(i, reg) accA = __builtin_amdgcn_mfma_f32_16x16x32_bf16( \
    __builtin_bit_cast(short8, reg), *(const short8*)(awp + (size_t)(i) * 512), accA, 0, 0, 0)
#define MFG(i, reg) accG = __builtin_amdgcn_mfma_f32_16x16x32_bf16( \
    __builtin_bit_cast(short8, reg), *(const short8*)(gwp + (size_t)(i) * 512), accG, 0, 0, 0)

#define ISSUE18() do { \
    const u16* _pr = p.preB + (size_t)tp1 * (B * P) + offPreF; \
    const u16* _ha = hAcur + offHF; \
    const u16* _hg = hGprev + offHF; \
    LDP(e0, _pr); LDP(e1, _pr + 1024); \
    LDC(e2, _ha); LDC(e3, _ha + 1024); LDC(e4, _ha + 2048); LDC(e5, _ha + 3072); \
    LDC(e6, _ha + 4096); LDC(e7, _ha + 5120); LDC(e8, _ha + 6144); LDC(e9, _ha + 7168); \
    LDC(e10, _hg); LDC(e11, _hg + 1024); LDC(e12, _hg + 2048); LDC(e13, _hg + 3072); \
    LDC(e14, _hg + 4096); LDC(e15, _hg + 5120); LDC(e16, _hg + 6144); LDC(e17, _hg + 7168); \
  } while (0)

  // ============ pre-phase: att gates for t=0 (ctx=0, hA=0 => only preB term) ============
  {
    const u16* _pr = p.preB + offPreF;
    float4v e0, e1;
    LDP(e0, _pr); LDP(e1, _pr + 1024);
    asm volatile("s_waitcnt vmcnt(0)" : "+v"(e0), "+v"(e1) :: "memory");
    float4v accA = {0.f, 0.f, 0.f, 0.f};
    MFA(0, e0); MFA(1, e1);
    float* r = sc + ((((0 * 2 + mt) * 4 + kqi) * 64 + lane) << 2);
    r[0] = accA[0]; r[1] = accA[1]; r[2] = accA[2]; r[3] = accA[3];
    __syncthreads();
    if (tid < 128) {
      int dj_l = (tid >> 5) & 3, mm = tid & 31;
      int dj = blk * 4 + dj_l;
      int mt2 = mm >> 4, m2 = mm & 15;
      float g4[4];
      #pragma unroll
      for (int gate = 0; gate < 4; ++gate) {
        int ln = ((m2 >> 2) << 4) | (dj_l * 4 + gate);
        int rg = m2 & 3;
        float s = 0.f;
        #pragma unroll
        for (int kk = 0; kk < 4; ++kk)
          s += sc[((((0 * 2 + mt2) * 4 + kk) * 64 + ln) << 2) + rg];
        g4[gate] = s + p.att_b[gate * D + dj];
      }
      float c  = cAl[dj_l * 32 + mm];
      float cn = sigmoidf(g4[1]) * c + sigmoidf(g4[0]) * tanhfast(g4[2]);
      float hn = sigmoidf(g4[3]) * tanhfast(cn);
      cAl[dj_l * 32 + mm] = cn;
      size_t offP = (size_t)(kqiB * 8 + rB) * 1024 + (size_t)(mm >> 4) * 512
                  + (size_t)(lhB * 16 + (mm & 15)) * 8 + j0B + dj_l;
      stc_u16(p.hAb0 + offP, f2bf(hn));
    }
  }
  gbar(p.bars, ++ep);

  // ============ main loop ============
  for (int t = 0; t < TDEC; ++t) {
    const u16* hAcur  = (t & 1) ? p.hAb1 : p.hAb0;
    u16*       hAnxt  = (t & 1) ? p.hAb0 : p.hAb1;
    const u16* hGprev = (t & 1) ? p.hGb0 : p.hGb1;
    u16*       hGcur  = (t & 1) ? p.hGb1 : p.hGb0;
    const int  tp1 = (t + 1 < TDEC) ? (t + 1) : (TDEC - 1);
    const bool doatt = (t < TDEC - 1);

    // PG activation fragments (issued at end of PA, waited in PG)
    float4v e0,e1,e2,e3,e4,e5,e6,e7,e8,e9,e10,e11,e12,e13,e14,e15,e16,e17;

    // ---- PA: group-distributed attention (8 blocks per batch) + frames ----
    {
      // 1) hA[b] gather -> hq fp32 (fragment-major, 1x16B per thread)
      if (tid < 128) {
        const int kqi2 = tid >> 5, r2 = (tid >> 2) & 7, lh2 = tid & 3;
        float4v hv = ldc1(hAcur + (size_t)(kqi2 * 8 + r2) * 1024 + (size_t)(b >> 4) * 512
                          + (size_t)(lh2 * 16 + (b & 15)) * 8);
        short8 hs = __builtin_bit_cast(short8, hv);
        #pragma unroll
        for (int j = 0; j < 8; ++j) hq[tid * 8 + j] = bf2f((u16)hs[j]);
      }
      __syncthreads();
      // 2) query = hA @ Wq.T (redundant per block; L2-warm weights)
      {
        const int a = tid >> 2, qk = tid & 3;
        const u16* wrow = p.wqb + (size_t)a * 1024 + qk * 256;
        const float* hh = hq + qk * 256;
        float a0 = 0.f, a1 = 0.f;
        #pragma unroll 4
        for (int i = 0; i < 32; i += 2) {
          short8 wv8 = *(const short8*)(wrow + i * 8);
          #pragma unroll
          for (int j = 0; j < 8; ++j) a0 += bf2f((u16)wv8[j]) * hh[i * 8 + j];
          short8 wv9 = *(const short8*)(wrow + (i + 1) * 8);
          #pragma unroll
          for (int j = 0; j < 8; ++j) a1 += bf2f((u16)wv9[j]) * hh[(i + 1) * 8 + j];
        }
        qpart[tid] = a0 + a1;
      }
      __syncthreads();
      if (tid < 128)
        query[tid] = qpart[tid * 4] + qpart[tid * 4 + 1] + qpart[tid * 4 + 2]
                   + qpart[tid * 4 + 3] + p.b_att[tid];
      // 3) location conv as MFMA, MY tiles only: tiles {k, k+8} (k<=4) or {k}
      const int tile0 = k, tile1 = k + 8;
      const int ntile = (k <= 4) ? 2 : 1;
      float4v cacc0 = {0.f, 0.f, 0.f, 0.f};
      float4v cacc1 = {0.f, 0.f, 0.f, 0.f};
      const int tn = wv, cl = lane & 15, kq8 = (lane >> 4) << 3;
      #pragma unroll
      for (int pass = 0; pass < 2; ++pass) {
        __syncthreads();
        const float* src = pass ? scm : sp;
        for (int i = tid; i < 6656; i += 512) {
          int r = i >> 5, kk = i & 31;
          float v = (r < 200 && kk < 31) ? src[r + kk] : 0.f;
          Abuf[i] = f2bf(v);
        }
        __syncthreads();
        short8 bfrag = *(const short8*)(p.kpk + ((size_t)(pass * 8 + tn) * 64 + lane) * 8);
        {
          short8 av = *(const short8*)(Abuf + (size_t)(tile0 * 16 + cl) * 32 + kq8);
          cacc0 = __builtin_amdgcn_mfma_f32_16x16x32_bf16(av, bfrag, cacc0, 0, 0, 0);
        }
        if (ntile == 2) {
          short8 av = *(const short8*)(Abuf + (size_t)(tile1 * 16 + cl) * 32 + kq8);
          cacc1 = __builtin_amdgcn_mfma_f32_16x16x32_bf16(av, bfrag, cacc1, 0, 0, 0);
        }
      }
      // 4) energies for MY tiles
      {
        const int a = tn * 16 + cl;
        const float qv = query[a];
        const float vv = p.v_att[a];
        #pragma unroll
        for (int i = 0; i < 4; ++i) {
          int tt = tile0 * 16 + ((lane >> 4) << 2) + i;
          float val = 0.f;
          if (tt < 200)
            val = tanhfast(qv + p.pm[((size_t)b * TENC + tt) * A + a] + cacc0[i]) * vv;
          val += __shfl_down(val, 8, 16);
          val += __shfl_down(val, 4, 16);
          val += __shfl_down(val, 2, 16);
          val += __shfl_down(val, 1, 16);
          if (cl == 0 && tt < 200) epart[tt * 8 + tn] = val;
        }
        if (ntile == 2) {
          #pragma unroll
          for (int i = 0; i < 4; ++i) {
            int tt = tile1 * 16 + ((lane >> 4) << 2) + i;
            float val = 0.f;
            if (tt < 200)
              val = tanhfast(qv + p.pm[((size_t)b * TENC + tt) * A + a] + cacc1[i]) * vv;
            val += __shfl_down(val, 8, 16);
            val += __shfl_down(val, 4, 16);
            val += __shfl_down(val, 2, 16);
            val += __shfl_down(val, 1, 16);
            if (cl == 0 && tt < 200) epart[tt * 8 + tn] = val;
          }
        }
      }
      __syncthreads();
      // 5) energy write to MALL exchange buffer
      {
        const int ntt = ntile * 16;
        if (tid < ntt) {
          int tile = (tid < 16) ? tile0 : tile1;
          int tt = tile * 16 + (tid & 15);
          if (tt < 200) {
            float e = epart[tt * 8 + 0] + epart[tt * 8 + 1] + epart[tt * 8 + 2]
                    + epart[tt * 8 + 3] + epart[tt * 8 + 4] + epart[tt * 8 + 5]
                    + epart[tt * 8 + 6] + epart[tt * 8 + 7];
            stc_f32(p.eps + (size_t)b * 256 + tt, e);
          }
        }
        asm volatile("s_waitcnt vmcnt(0)" ::: "memory");
      }
      __syncthreads();
      if (tid == 0) atomicAdd(p.gc + (size_t)b * 32, 1u);
      // 6) frame(t-1) for batch b while the group converges
      if (t > 0) frame_group(p, t - 1, b, k, wv, lane, tid, Xf);
      // 7) group sync: wait all 8 slices of batch b
      if (tid == 0) {
        while (__hip_atomic_load(p.gc + (size_t)b * 32, __ATOMIC_RELAXED,
                                 __HIP_MEMORY_SCOPE_AGENT) < 8u * (unsigned)(t + 1))
          __builtin_amdgcn_s_sleep(1);
      }
      __syncthreads();
      // 8) read full energies, mask
      const int len = p.lens[b];
      if (tid < 200) {
        float e = ldc_f32(p.eps + (size_t)b * 256 + tid);
        e_w[tid] = (tid < len) ? e : -1.0e9f;
      }
      __syncthreads();
      // 9) softmax over 200 (redundant per block)
      float lm = (tid < 200) ? e_w[tid] : -3.0e38f;
      for (int o = 32; o > 0; o >>= 1) lm = fmaxf(lm, __shfl_down(lm, o, 64));
      if (lane == 0) red[wv] = lm;
      __syncthreads();
      float gm = red[0];
      #pragma unroll
      for (int i = 1; i < 8; ++i) gm = fmaxf(gm, red[i]);
      float ls = 0.f;
      float myp = 0.f;
      if (tid < 200) { myp = __expf(e_w[tid] - gm); ls = myp; }
      __syncthreads();
      if (tid < 200) e_w[tid] = myp;
      for (int o = 32; o > 0; o >>= 1) ls += __shfl_down(ls, o, 64);
      if (lane == 0) red[wv] = ls;
      __syncthreads();
      float inv = 0.f;
      #pragma unroll
      for (int i = 0; i < 8; ++i) inv += red[i];
      inv = 1.0f / inv;
      __syncthreads();
      if (tid < 200) {
        float wval = e_w[tid] * inv;
        e_w[tid] = wval;
        sp[15 + tid] = wval;
        scm[15 + tid] += wval;
        if (k == 0)
          p.out[ALIGN_OFF + ((size_t)b * TDEC + t) * TENC + tid] = wval;
      }
      __syncthreads();
      // 10) context slice: cols [64k, 64k+64), tt-slice [25*wv, 25*wv+25)
      {
        const int c = (k << 6) + lane;
        const float* ebase = p.enc + ((size_t)b * TENC + (size_t)(wv * 25)) * E + c;
        const float* ew = e_w + wv * 25;
        float a0 = 0.f, a1 = 0.f, a2 = 0.f, a3 = 0.f, a4 = 0.f;
        #pragma unroll
        for (int i = 0; i < 25; i += 5) {
          a0 += ew[i]     * ebase[(size_t)i * E];
          a1 += ew[i + 1] * ebase[(size_t)(i + 1) * E];
          a2 += ew[i + 2] * ebase[(size_t)(i + 2) * E];
          a3 += ew[i + 3] * ebase[(size_t)(i + 3) * E];
          a4 += ew[i + 4] * ebase[(size_t)(i + 4) * E];
        }
        cpart[(wv << 6) + lane] = ((a0 + a1) + (a2 + a3)) + a4;
      }
      __syncthreads();
      if (tid < 64) {
        float ssum = 0.f;
        #pragma unroll
        for (int s2 = 0; s2 < 8; ++s2) ssum += cpart[(s2 << 6) + tid];
        csum[tid] = ssum;
      }
      __syncthreads();
      if (tid < 16) {
        float4v v = { csum[tid * 4], csum[tid * 4 + 1], csum[tid * 4 + 2], csum[tid * 4 + 3] };
        stc_16B(p.ctxf + (size_t)(t & 1) * (E * B) + (size_t)b * 512
                + (size_t)(k << 6) + (size_t)tid * 4, v);
      }
      if (tid < 8) {
        const int q = 2 * k + (tid >> 2), lh = tid & 3;
        const int cb = tid * 8;
        unsigned w0 = (unsigned)f2bf(csum[cb])     | ((unsigned)f2bf(csum[cb + 1]) << 16);
        unsigned w1 = (unsigned)f2bf(csum[cb + 2]) | ((unsigned)f2bf(csum[cb + 3]) << 16);
        unsigned w2 = (unsigned)f2bf(csum[cb + 4]) | ((unsigned)f2bf(csum[cb + 5]) << 16);
        unsigned w3 = (unsigned)f2bf(csum[cb + 6]) | ((unsigned)f2bf(csum[cb + 7]) << 16);
        float4v pk;
        pk[0] = __builtin_bit_cast(float, w0);
        pk[1] = __builtin_bit_cast(float, w1);
        pk[2] = __builtin_bit_cast(float, w2);
        pk[3] = __builtin_bit_cast(float, w3);
        stc_16B(p.ctxb + (size_t)q * 1024 + (size_t)(b >> 4) * 512
                + (size_t)(lh * 16 + (b & 15)) * 8, pk);
      }
      // 11) issue PG fragment loads (stream overlaps barrier + PG head)
      ISSUE18();
    }
    gbar(p.bars, ++ep);

    // ---- PG: gen gates t + att gates t+1 (all 256 blocks) ----
    {
      const u16* _ct = p.ctxb + offCF;
      float4v c0, c1, c2, c3;
      LDC(c0, _ct); LDC(c1, _ct + 1024); LDC(c2, _ct + 2048); LDC(c3, _ct + 3072);
      // fragments first (ctx still in flight)
      asm volatile("s_waitcnt vmcnt(4)"
        : "+v"(e0),"+v"(e1),"+v"(e2),"+v"(e3),"+v"(e4),"+v"(e5),"+v"(e6),"+v"(e7),
          "+v"(e8),"+v"(e9),"+v"(e10),"+v"(e11),"+v"(e12),"+v"(e13),"+v"(e14),"+v"(e15),
          "+v"(e16),"+v"(e17)
        :: "memory");
      float4v accA = {0.f, 0.f, 0.f, 0.f};
      float4v accG = {0.f, 0.f, 0.f, 0.f};
      MFA(0, e0);  MFA(1, e1);
      MFA(2, e2);  MFG(0, e2);
      MFA(3, e3);  MFG(1, e3);
      MFA(4, e4);  MFG(2, e4);
      MFA(5, e5);  MFG(3, e5);
      MFA(6, e6);  MFG(4, e6);
      MFA(7, e7);  MFG(5, e7);
      MFA(8, e8);  MFG(6, e8);
      MFA(9, e9);  MFG(7, e9);
      MFG(8, e10); MFG(9, e11); MFG(10, e12); MFG(11, e13);
      MFG(12, e14); MFG(13, e15); MFG(14, e16); MFG(15, e17);
      __builtin_amdgcn_sched_barrier(0);
      asm volatile("s_waitcnt vmcnt(0)"
        : "+v"(c0),"+v"(c1),"+v"(c2),"+v"(c3) :: "memory");
      MFA(10, c0); MFG(16, c0);
      MFA(11, c1); MFG(17, c1);
      MFA(12, c2); MFG(18, c2);
      MFA(13, c3); MFG(19, c3);
      float* rA = sc + ((((0 * 2 + mt) * 4 + kqi) * 64 + lane) << 2);
      rA[0] = accA[0]; rA[1] = accA[1]; rA[2] = accA[2]; rA[3] = accA[3];
      float* rG = sc + ((((1 * 2 + mt) * 4 + kqi) * 64 + lane) << 2);
      rG[0] = accG[0]; rG[1] = accG[1]; rG[2] = accG[2]; rG[3] = accG[3];
      __syncthreads();
      if (tid < 256) {
        const int gg = tid >> 7, dj_l = (tid >> 5) & 3, mm = tid & 31;
        if (gg == 1 || doatt) {
          const int dj = blk * 4 + dj_l;
          const int mt2 = mm >> 4, m2 = mm & 15;
          const float* bias = (gg == 0) ? p.att_b : p.gen_b;
          float g4[4];
          #pragma unroll
          for (int gate = 0; gate < 4; ++gate) {
            int ln = ((m2 >> 2) << 4) | (dj_l * 4 + gate);
            int rg = m2 & 3;
            float s = 0.f;
            #pragma unroll
            for (int kk = 0; kk < 4; ++kk)
              s += sc[((((gg * 2 + mt2) * 4 + kk) * 64 + ln) << 2) + rg];
            g4[gate] = s + bias[gate * D + dj];
          }
          float* cl2 = (gg == 0) ? cAl : cGl;
          float c  = cl2[dj_l * 32 + mm];
          float cn = sigmoidf(g4[1]) * c + sigmoidf(g4[0]) * tanhfast(g4[2]);
          float hn = sigmoidf(g4[3]) * tanhfast(cn);
          cl2[dj_l * 32 + mm] = cn;
          hstg[tid] = hn;
        }
      }
      __syncthreads();
      // packed fragment-major stores: 64 threads, 8B/16B transactions
      if (tid < 64) {
        const int gg = tid >> 5, mm = tid & 31;
        const size_t offP = (size_t)(kqiB * 8 + rB) * 1024 + (size_t)(mm >> 4) * 512
                          + (size_t)(lhB * 16 + (mm & 15)) * 8 + j0B;
        if (gg == 0) {
          if (doatt) {
            unsigned w0 = (unsigned)f2bf(hstg[mm])      | ((unsigned)f2bf(hstg[32 + mm]) << 16);
            unsigned w1 = (unsigned)f2bf(hstg[64 + mm]) | ((unsigned)f2bf(hstg[96 + mm]) << 16);
            uint2v pk = {w0, w1};
            stc_8B(hAnxt + offP, pk);
          }
        } else {
          float f0 = hstg[128 + mm], f1 = hstg[160 + mm];
          float f2 = hstg[192 + mm], f3 = hstg[224 + mm];
          unsigned w0 = (unsigned)f2bf(f0) | ((unsigned)f2bf(f1) << 16);
          unsigned w1 = (unsigned)f2bf(f2) | ((unsigned)f2bf(f3) << 16);
          uint2v pk = {w0, w1};
          stc_8B(hGcur + offP, pk);
          float4v pf = {f0, f1, f2, f3};
          stc_16B(p.hGf + (size_t)mm * 1024 + blk * 4, pf);
        }
      }
    }
    gbar(p.bars, ++ep);
  }

  // ---- final frame (ft = 599), group-distributed ----
  frame_group(p, TDEC - 1, b, k, wv, lane, tid, Xf);
}

// ---------------------------------------------------------------------------
// Prenet -> preB fragment-major per t
__global__ __launch_bounds__(256) void prenet_kernel(
    const float* __restrict__ target, const float* __restrict__ W1, const float* __restrict__ b1,
    const float* __restrict__ W2, const float* __restrict__ b2, u16* __restrict__ preB)
{
  const int t = blockIdx.x;
  const int tid = threadIdx.x;
  __shared__ float tg[B][M];
  __shared__ float x1[B][P];
  for (int i = tid; i < B * M; i += 256) {
    int b = i / M, m = i - b * M;
    tg[b][m] = (t == 0) ? 0.0f : target[(size_t)b * M * TDEC + (size_t)m * TDEC + (t - 1)];
  }
  __syncthreads();
  for (int i = tid; i < B * P; i += 256) {
    int b = i >> 8, j = i & 255;
    const float* w = W1 + (size_t)j * M;
    float acc = b1[j];
    for (int m = 0; m < M; ++m) acc += w[m] * tg[b][m];
    x1[b][j] = fmaxf(acc, 0.0f);
  }
  __syncthreads();
  for (int i = tid; i < B * P; i += 256) {
    int b = i >> 8, j = i & 255;
    const float* w = W2 + (size_t)j * P;
    float acc = b2[j];
    for (int m = 0; m < P; m += 4)
      acc += w[m]*x1[b][m] + w[m+1]*x1[b][m+1] + w[m+2]*x1[b][m+2] + w[m+3]*x1[b][m+3];
    int kqi = j >> 6, r = (j >> 5) & 1, lh = (j >> 3) & 3, jj = j & 7;
    size_t off = (size_t)(kqi * 2 + r) * 1024 + (size_t)(b >> 4) * 512
               + (size_t)(lh * 16 + (b & 15)) * 8 + jj;
    preB[(size_t)t * (B * P) + off] = f2bf(fmaxf(acc, 0.0f));
  }
}

// ---------------------------------------------------------------------------
__global__ __launch_bounds__(256) void procmem_kernel(
    const float* __restrict__ enc, const float* __restrict__ Wm, float* __restrict__ pm)
{
  const int blk = blockIdx.x;
  const int b = blk >> 3;
  const int t0 = (blk & 7) * 25;
  for (int i = threadIdx.x; i < 25 * A; i += 256) {
    int tl = i >> 7, a = i & 127;
    int t = t0 + tl;
    const float* x = enc + ((size_t)b * TENC + t) * E;
    const float* w = Wm + (size_t)a * E;
    float acc = 0.0f;
    for (int k = 0; k < E; k += 4)
      acc += w[k]*x[k] + w[k+1]*x[k+1] + w[k+2]*x[k+2] + w[k+3]*x[k+3];
    pm[((size_t)b * TENC + t) * A + a] = acc;
  }
}

// ---------------------------------------------------------------------------
__global__ __launch_bounds__(256) void kpk_kernel(
    const float* __restrict__ lker, const float* __restrict__ Wloc, u16* __restrict__ kpk)
{
  int idx = blockIdx.x * 256 + threadIdx.x;
  if (idx >= 8192) return;
  int j = idx & 7, ln = (idx >> 3) & 63, tn = (idx >> 9) & 7, pass = idx >> 12;
  int a = tn * 16 + (ln & 15);
  int k = ((ln >> 4) << 3) + j;
  float v = 0.f;
  if (k < KC) {
    for (int f = 0; f < LF; ++f)
      v += Wloc[a * LF + f] * lker[f * (2 * KC) + pass * KC + k];
  }
  kpk[idx] = f2bf(v);
}

// ---------------------------------------------------------------------------
__global__ __launch_bounds__(256) void wqpack_kernel(
    const float* __restrict__ Wq, u16* __restrict__ wqb)
{
  int idx = blockIdx.x * 256 + threadIdx.x;
  if (idx < A * D) wqb[idx] = f2bf(Wq[idx]);
}

// ---------------------------------------------------------------------------
// fwb[j][k]: j=0..79 frame rows, j=80 stop row; bf16
__global__ __launch_bounds__(256) void fwpack_kernel(
    const float* __restrict__ frame_W, const float* __restrict__ stop_W, u16* __restrict__ fwb)
{
  int idx = blockIdx.x * 256 + threadIdx.x;
  if (idx >= 81 * 1536) return;
  int j = idx / 1536, k = idx - j * 1536;
  float v = (j < M) ? frame_W[(size_t)j * 1536 + k] : stop_W[k];
  fwb[idx] = f2bf(v);
}

// ---------------------------------------------------------------------------
extern "C" void kernel_launch(void* const* d_in, const int* in_sizes, int n_in,
                              void* d_out, int out_size, void* d_ws, size_t ws_size,
                              hipStream_t stream)
{
  const float* enc      = (const float*)d_in[0];
  const int*   lens     = (const int*)  d_in[1];
  const float* target   = (const float*)d_in[2];
  const float* pW1      = (const float*)d_in[4];
  const float* pb1      = (const float*)d_in[5];
  const float* pW2      = (const float*)d_in[6];
  const float* pb2      = (const float*)d_in[7];
  const float* att_Wih  = (const float*)d_in[8];
  const float* att_Whh  = (const float*)d_in[9];
  const float* att_b    = (const float*)d_in[10];
  const float* gen_Wih  = (const float*)d_in[11];
  const float* gen_Whh  = (const float*)d_in[12];
  const float* gen_b    = (const float*)d_in[13];
  const float* Wq       = (const float*)d_in[14];
  const float* Wm       = (const float*)d_in[15];
  const float* lker     = (const float*)d_in[16];
  const float* Wloc     = (const float*)d_in[17];
  const float* v_att    = (const float*)d_in[18];
  const float* b_att    = (const float*)d_in[19];
  const float* frame_W  = (const float*)d_in[20];
  const float* frame_b  = (const float*)d_in[21];
  const float* stop_W   = (const float*)d_in[22];
  const float* stop_b   = (const float*)d_in[23];

  float* ws = (float*)d_ws;
  float* st = ws + OFF_ST;

  Params p;
  p.enc = enc; p.lens = lens;
  p.att_Wih = att_Wih; p.att_Whh = att_Whh; p.att_b = att_b;
  p.gen_Wih = gen_Wih; p.gen_Whh = gen_Whh; p.gen_b = gen_b;
  p.v_att = v_att; p.b_att = b_att;
  p.frame_b = frame_b; p.stop_b = stop_b;
  p.pm   = ws + OFF_PM;
  p.preB = (const u16*)(ws + OFF_PREB);
  p.kpk  = (const u16*)(ws + OFF_KPK);
  p.wqb  = (const u16*)(ws + OFF_WQB);
  p.fwb  = (const u16*)(ws + OFF_FWB);
  p.hAb0 = (u16*)(st + ST_HAB0);
  p.hAb1 = (u16*)(st + ST_HAB1);
  p.hGb0 = (u16*)(st + ST_HGB0);
  p.hGb1 = (u16*)(st + ST_HGB1);
  p.ctxb = (u16*)(st + ST_CTXB);
  p.ctxf = st + ST_CTXF;
  p.hGf  = st + ST_HGF;
  p.bars = (unsigned*)(st + ST_BARS);
  p.eps  = st + ST_EPS;
  p.gc   = (unsigned*)(st + ST_GC);
  p.out  = (float*)d_out;

  hipMemsetAsync((void*)st, 0, N_STATE * sizeof(float), stream);

  kpk_kernel    <<<32, 256, 0, stream>>>(lker, Wloc, (u16*)(ws + OFF_KPK));
  wqpack_kernel <<<512, 256, 0, stream>>>(Wq, (u16*)(ws + OFF_WQB));
  fwpack_kernel <<<486, 256, 0, stream>>>(frame_W, stop_W, (u16*)(ws + OFF_FWB));
  prenet_kernel <<<TDEC, 256, 0, stream>>>(target, pW1, pb1, pW2, pb2, (u16*)(ws + OFF_PREB));
  procmem_kernel<<<256, 256, 0, stream>>>(enc, Wm, ws + OFF_PM);

  hipFuncSetAttribute((const void*)persist_kernel,
                      hipFuncAttributeMaxDynamicSharedMemorySize, SMEM_BYTES);
  persist_kernel<<<256, 512, SMEM_BYTES, stream>>>(p);
}